// Round 3
// baseline (25964.713 us; speedup 1.0000x reference)
//
#include <hip/hip_runtime.h>
#include <stdint.h>

// LSTM classifier: VOCAB=32000, H=512, LAYERS=2, LABELS=4, B=32, T=2048
#define TSEQ 2048
#define BATCH 32
#define HID 512
#define NWGL 64          // WGs per layer (8 hidden units each)
#define NWG_ALL 128

typedef _Float16 half8 __attribute__((ext_vector_type(8)));
typedef float floatx4 __attribute__((ext_vector_type(4)));

__device__ __forceinline__ float sigf(float x){ return 1.f/(1.f+__expf(-x)); }
__device__ __forceinline__ float tanh_(float x){
  float e = __expf(-2.f*fabsf(x));
  float r = (1.f-e)/(1.f+e);
  return x<0.f ? -r : r;
}
__device__ __forceinline__ void gload_lds16(const _Float16* src, _Float16* dst){
  __builtin_amdgcn_global_load_lds((const __attribute__((address_space(1))) void*)src,
      (__attribute__((address_space(3))) void*)dst, 16, 0, 0);
}

// ---------------- emb f32 -> f16 (flat convert, 16.38M elements)
__global__ void k_cvt_emb(const float* __restrict__ in, _Float16* __restrict__ out, int n8){
  int i = blockIdx.x*256 + threadIdx.x;
  if (i < n8){
    const float4* s = (const float4*)(in + (size_t)i*8);
    float4 a = s[0], b = s[1];
    half8 o = {(_Float16)a.x,(_Float16)a.y,(_Float16)a.z,(_Float16)a.w,
               (_Float16)b.x,(_Float16)b.y,(_Float16)b.z,(_Float16)b.w};
    *(half8*)(out + (size_t)i*8) = o;
  }
}

// ---------------- fused 2-layer persistent LSTM, 128 WGs, 1-step pipeline skew
// WG owns 8 hidden units of one layer => 32 gate rows, remapped so that
// grow(m) = (m&3)*512 + wg*8 + (m>>2)  (gate = m&3, unit = m>>2)
// => C-fragment regs r=0..3 of thread (mh,nh,kg,r15) are the 4 gates of
//    unit u = mh*4+kg, batch b = nh*16+r15  -> in-register LSTM cell update.
__global__ void __launch_bounds__(256) k_main(
    const int* __restrict__ xtok, const _Float16* __restrict__ emb16,
    const float* __restrict__ Wih, const float* __restrict__ Whh,
    const float* __restrict__ bih, const float* __restrict__ bhh,
    _Float16* __restrict__ h0ring, _Float16* __restrict__ h1ring,
    float* __restrict__ hT, unsigned* bar){
  __shared__ _Float16 Wxl[32*512] __attribute__((aligned(16)));  // W_ih slice, frag order
  __shared__ _Float16 Whl[32*512] __attribute__((aligned(16)));  // W_hh slice, frag order
  __shared__ _Float16 xl [32*512] __attribute__((aligned(16)));  // x_t  staged [32][512]
  __shared__ _Float16 hl [32*512] __attribute__((aligned(16)));  // h_{t-1} staged
  int tid = threadIdx.x, lane = tid&63, wave = tid>>6;
  int wgAll = blockIdx.x;
  int layer = wgAll>>6, wg = wgAll&63;
  int mh = wave>>1, nh = wave&1;
  int kg = lane>>4, r15 = lane&15;

  // ---- stage both weight slices (f32 -> f16, frag order)
  for (int i=0;i<8;++i){
    int c = tid + i*256;                 // [0,2048): m = tile row, k = chunk*8
    int m = c>>6, k = (c&63)<<3;
    int grow = ((m&3)<<9) + (wg<<3) + (m>>2);
    int didx = (((k>>5)*2 + (m>>4))<<9) + ((((k>>3)&3)<<4) + (m&15))*8;
    const float4* s0 = (const float4*)(Wih + ((size_t)layer*2048 + grow)*HID + k);
    float4 a0 = s0[0], b0 = s0[1];
    *(half8*)(Wxl + didx) = half8{(_Float16)a0.x,(_Float16)a0.y,(_Float16)a0.z,(_Float16)a0.w,
                                  (_Float16)b0.x,(_Float16)b0.y,(_Float16)b0.z,(_Float16)b0.w};
    const float4* s1 = (const float4*)(Whh + ((size_t)layer*2048 + grow)*HID + k);
    float4 a1 = s1[0], b1 = s1[1];
    *(half8*)(Whl + didx) = half8{(_Float16)a1.x,(_Float16)a1.y,(_Float16)a1.z,(_Float16)a1.w,
                                  (_Float16)b1.x,(_Float16)b1.y,(_Float16)b1.z,(_Float16)b1.w};
  }
  int u = (mh<<2) + kg;                  // owned hidden unit (0..7)
  int bcol = (nh<<4) + r15;              // owned batch (0..31)
  float bias[4];
  #pragma unroll
  for (int r=0;r<4;++r){
    int grow = (r<<9) + (wg<<3) + u;
    bias[r] = bih[layer*2048 + grow] + bhh[layer*2048 + grow];
  }
  __syncthreads();

  unsigned* cnt  = bar;                  // 8 counters, stride 32 uints (128B)
  unsigned* gcnt = bar + 320;
  unsigned* gen  = bar + 384;
  int grp = wgAll & 7;

  float c_st = 0.f;
  int tb0 = 0, tb1 = 0, tb0n = 0, tb1n = 0;
  if (layer == 0){ tb0n = xtok[r15*TSEQ]; tb1n = xtok[(16+r15)*TSEQ]; }

  for (int tt=0; tt<=TSEQ; ++tt){
    bool act = (layer==0) ? (tt < TSEQ) : (tt >= 1);
    int t = (layer==0) ? tt : tt-1;
    if (act){
      // ---- stage x_t
      if (layer == 0){
        tb0 = tb0n; tb1 = tb1n;
        if (tt+1 < TSEQ){ tb0n = xtok[r15*TSEQ + tt+1]; tb1n = xtok[(16+r15)*TSEQ + tt+1]; }
        #pragma unroll
        for (int i=0;i<8;++i){
          int blk = wave*8+i; int ks = blk>>1, bh = blk&1;
          int tok = bh ? tb1 : tb0;
          gload_lds16(emb16 + (size_t)tok*HID + ks*32 + kg*8, xl + blk*512);
        }
      } else {
        const _Float16* base = h0ring + (size_t)(t&3)*(BATCH*HID);
        #pragma unroll
        for (int i=0;i<8;++i){
          int blk = wave*8+i; int ks = blk>>1, bh = blk&1;
          gload_lds16(base + (size_t)(bh*16+r15)*HID + ks*32 + kg*8, xl + blk*512);
        }
      }
      // ---- stage h_{t-1}
      if (t > 0){
        const _Float16* base = (layer ? h1ring : h0ring) + (size_t)((t-1)&3)*(BATCH*HID);
        #pragma unroll
        for (int i=0;i<8;++i){
          int blk = wave*8+i; int ks = blk>>1, bh = blk&1;
          gload_lds16(base + (size_t)(bh*16+r15)*HID + ks*32 + kg*8, hl + blk*512);
        }
      }
      __syncthreads();
      // ---- gates = Wih*x (+ Whh*h) ; two 16-MFMA chains
      floatx4 acc = {0.f,0.f,0.f,0.f};
      #pragma unroll
      for (int ks=0; ks<16; ++ks){
        half8 a = *(const half8*)(Wxl + (ks*2+mh)*512 + lane*8);
        half8 b = *(const half8*)(xl  + (ks*2+nh)*512 + lane*8);
        acc = __builtin_amdgcn_mfma_f32_16x16x32_f16(a, b, acc, 0,0,0);
      }
      if (t > 0){
        #pragma unroll
        for (int ks=0; ks<16; ++ks){
          half8 a = *(const half8*)(Whl + (ks*2+mh)*512 + lane*8);
          half8 b = *(const half8*)(hl  + (ks*2+nh)*512 + lane*8);
          acc = __builtin_amdgcn_mfma_f32_16x16x32_f16(a, b, acc, 0,0,0);
        }
      }
      // ---- in-register cell update (gates i,f,g,o = regs 0..3)
      float gi = acc[0]+bias[0], gf = acc[1]+bias[1];
      float gg = acc[2]+bias[2], go = acc[3]+bias[3];
      c_st = sigf(gf)*c_st + sigf(gi)*tanh_(gg);
      float h = sigf(go)*tanh_(c_st);
      _Float16* ring = layer ? h1ring : h0ring;
      ring[(size_t)(t&3)*(BATCH*HID) + (size_t)bcol*HID + (wg<<3) + u] = (_Float16)h;
      if (layer==1 && t==TSEQ-1) hT[bcol*HID + (wg<<3) + u] = h;
      __syncthreads();                   // drain h stores before release
    }
    if (tt < TSEQ){
      // ---- two-level grid barrier (16 per group line + 8 global)
      if (tid == 0){
        __threadfence();                 // release (cross-XCD writeback)
        unsigned g = __hip_atomic_load(gen, __ATOMIC_RELAXED, __HIP_MEMORY_SCOPE_AGENT);
        unsigned p = __hip_atomic_fetch_add(&cnt[grp*32], 1u, __ATOMIC_ACQ_REL, __HIP_MEMORY_SCOPE_AGENT);
        bool released = false;
        if (p == 15u){
          unsigned q = __hip_atomic_fetch_add(gcnt, 1u, __ATOMIC_ACQ_REL, __HIP_MEMORY_SCOPE_AGENT);
          if (q == 7u){
            #pragma unroll
            for (int j=0;j<8;++j)
              __hip_atomic_store(&cnt[j*32], 0u, __ATOMIC_RELAXED, __HIP_MEMORY_SCOPE_AGENT);
            __hip_atomic_store(gcnt, 0u, __ATOMIC_RELAXED, __HIP_MEMORY_SCOPE_AGENT);
            __hip_atomic_fetch_add(gen, 1u, __ATOMIC_RELEASE, __HIP_MEMORY_SCOPE_AGENT);
            released = true;
          }
        }
        if (!released){
          while (__hip_atomic_load(gen, __ATOMIC_RELAXED, __HIP_MEMORY_SCOPE_AGENT) == g)
            __builtin_amdgcn_s_sleep(2);
        }
        __threadfence();                 // acquire (invalidate stale caches)
      }
      __syncthreads();
    }
  }
}

// ---------------- classifier + log_softmax + NLL loss
__global__ void k_cls(const float* __restrict__ hT, const float* __restrict__ fcw,
                      const float* __restrict__ fcb, const int* __restrict__ labels,
                      float* __restrict__ out){
  __shared__ float lg[128];
  __shared__ float ls[32];
  int tid = threadIdx.x;
  if (tid < 128){
    int b = tid>>2, n = tid&3;
    const float4* hp = (const float4*)(hT + b*HID);
    const float4* wp = (const float4*)(fcw + n*HID);
    float s = 0.f;
    for (int k=0;k<128;++k){ float4 a = hp[k], w = wp[k];
      s += a.x*w.x + a.y*w.y + a.z*w.z + a.w*w.w; }
    lg[tid] = s + fcb[n];
  }
  __syncthreads();
  if (tid < 32){
    float x0 = lg[tid*4+0], x1 = lg[tid*4+1], x2 = lg[tid*4+2], x3 = lg[tid*4+3];
    float mx = fmaxf(fmaxf(x0,x1),fmaxf(x2,x3));
    float lse = mx + logf(__expf(x0-mx)+__expf(x1-mx)+__expf(x2-mx)+__expf(x3-mx));
    ls[tid] = lse - lg[tid*4 + labels[tid]];
  }
  __syncthreads();
  if (tid == 0){
    float s = 0.f;
    for (int b=0;b<32;++b) s += ls[b];
    out[0] = s * (1.f/32.f);
  }
  if (tid < 128) out[1+tid] = lg[tid];
}

extern "C" void kernel_launch(void* const* d_in, const int* in_sizes, int n_in,
                              void* d_out, int out_size, void* d_ws, size_t ws_size,
                              hipStream_t stream) {
  const int*   x      = (const int*)d_in[0];
  const int*   labels = (const int*)d_in[1];
  const float* emb    = (const float*)d_in[2];
  const float* Wih    = (const float*)d_in[3];
  const float* Whh    = (const float*)d_in[4];
  const float* bih    = (const float*)d_in[5];
  const float* bhh    = (const float*)d_in[6];
  const float* fcw    = (const float*)d_in[7];
  const float* fcb    = (const float*)d_in[8];
  float* out = (float*)d_out;
  char* ws = (char*)d_ws;

  _Float16* emb16  = (_Float16*)(ws);                         // 31.25MB used
  _Float16* h0ring = (_Float16*)(ws + (32ull<<20));           // 128KB
  _Float16* h1ring = (_Float16*)(ws + (32ull<<20) + (128<<10)); // 128KB
  float*    hT     = (float*)   (ws + (32ull<<20) + (256<<10)); // 64KB
  unsigned* bar    = (unsigned*)(ws + (32ull<<20) + (320<<10)); // 2KB

  hipMemsetAsync(bar, 0, 2048, stream);
  k_cvt_emb<<<8000, 256, 0, stream>>>(emb, emb16, 2048000);
  k_main<<<NWG_ALL, 256, 0, stream>>>(x, emb16, Wih, Whh, bih, bhh,
                                      h0ring, h1ring, hT, bar);
  k_cls<<<1, 256, 0, stream>>>(hT, fcw, fcb, labels, out);
}

// Round 4
// 20310.091 us; speedup vs baseline: 1.2784x; 1.2784x over previous
//
#include <hip/hip_runtime.h>
#include <stdint.h>

// LSTM classifier: VOCAB=32000, H=512, LAYERS=2, LABELS=4, B=32, T=2048
#define TSEQ 2048
#define BATCH 32
#define HID 512
#define NWG_ALL 128      // 64 WGs per layer, each owns 8 hidden units (32 gate rows)

typedef _Float16 half8 __attribute__((ext_vector_type(8)));
typedef float floatx4 __attribute__((ext_vector_type(4)));

__device__ __forceinline__ float sigf(float x){ return 1.f/(1.f+__expf(-x)); }
__device__ __forceinline__ float tanh_(float x){
  float e = __expf(-2.f*fabsf(x));
  float r = (1.f-e)/(1.f+e);
  return x<0.f ? -r : r;
}
__device__ __forceinline__ half8 cvt8(float4 a, float4 b){
  return half8{(_Float16)a.x,(_Float16)a.y,(_Float16)a.z,(_Float16)a.w,
               (_Float16)b.x,(_Float16)b.y,(_Float16)b.z,(_Float16)b.w};
}

// ---------------- emb f32 -> f16 (flat convert)
__global__ void k_cvt_emb(const float* __restrict__ in, _Float16* __restrict__ out, int n8){
  int i = blockIdx.x*256 + threadIdx.x;
  if (i < n8){
    const float4* s = (const float4*)(in + (size_t)i*8);
    *(half8*)(out + (size_t)i*8) = cvt8(s[0], s[1]);
  }
}

// ---------------- fused 2-layer persistent LSTM, register-resident weights,
// no LDS, flag-array grid barrier, x-projection prefetched under the wait.
// Gate-row remap: grow(m) = (m&3)*512 + wg*8 + (m>>2); C-frag regs r=0..3 of
// thread (mh,nh,kg,r15) = gates i,f,g,o of unit u=mh*4+kg, batch b=nh*16+r15.
// Layer 1 runs with skew 2: at tick tt it computes step t=tt-2.
__global__ void __launch_bounds__(256,1) k_main(
    const int* __restrict__ xtok, const _Float16* __restrict__ emb16,
    const float* __restrict__ Wih, const float* __restrict__ Whh,
    const float* __restrict__ bih, const float* __restrict__ bhh,
    _Float16* __restrict__ h0ring, _Float16* __restrict__ h1ring,
    float* __restrict__ hT, unsigned* __restrict__ flags){
  int tid = threadIdx.x, lane = tid&63, wave = tid>>6;
  int wgAll = blockIdx.x, layer = wgAll>>6, wg = wgAll&63;
  int mh = wave>>1, nh = wave&1;
  int kg = lane>>4, r15 = lane&15;
  int bcol = nh*16 + r15;           // owned batch column
  int u = mh*4 + kg;                // owned hidden unit (0..7)

  // ---- one-time: weight A-fragments into registers (f32 -> f16)
  half8 wx[16], wh[16];
  {
    int m = mh*16 + r15;            // A-frag row
    int grow = ((m&3)<<9) + (wg<<3) + (m>>2);
    const float* pwx = Wih + ((size_t)layer*2048 + grow)*HID + kg*8;
    const float* pwh = Whh + ((size_t)layer*2048 + grow)*HID + kg*8;
    #pragma unroll
    for (int ks=0; ks<16; ++ks){
      wx[ks] = cvt8(*(const float4*)(pwx + ks*32), *(const float4*)(pwx + ks*32 + 4));
      wh[ks] = cvt8(*(const float4*)(pwh + ks*32), *(const float4*)(pwh + ks*32 + 4));
    }
  }
  float bias[4];
  #pragma unroll
  for (int r=0; r<4; ++r){
    int g = layer*2048 + (r<<9) + (wg<<3) + u;
    bias[r] = bih[g] + bhh[g];
  }

  uint32_t* myring32 = (uint32_t*)(layer ? h1ring : h0ring);
  const _Float16* hring = layer ? h1ring : h0ring;

  // ---- prologue: x-projection for first active tick
  floatx4 accx = {bias[0], bias[1], bias[2], bias[3]};
  if (layer == 0){
    int tok = xtok[bcol*TSEQ + 0];
    const _Float16* px = emb16 + (size_t)tok*HID + kg*8;
    #pragma unroll
    for (int ks=0; ks<16; ++ks){
      half8 xf = *(const half8*)(px + ks*32);
      accx = __builtin_amdgcn_mfma_f32_16x16x32_f16(wx[ks], xf, accx, 0,0,0);
    }
  }

  float c_st = 0.f;
  for (int tt=0; tt<=TSEQ+1; ++tt){
    bool act = (layer==0) ? (tt < TSEQ) : (tt >= 2);
    int t = (layer==0) ? tt : tt-2;
    if (act){
      floatx4 acc = accx;
      if (t > 0){
        // h_{t-1} B-fragments straight from ring (fresh: first touch since inv)
        const _Float16* hb = hring + (size_t)((t-1)&7)*(BATCH*HID) + bcol*HID + kg*8;
        half8 hf[16];
        #pragma unroll
        for (int ks=0; ks<16; ++ks) hf[ks] = *(const half8*)(hb + ks*32);
        #pragma unroll
        for (int ks=0; ks<16; ++ks)
          acc = __builtin_amdgcn_mfma_f32_16x16x32_f16(wh[ks], hf[ks], acc, 0,0,0);
      }
      float gi = acc[0], gf = acc[1], gg = acc[2], go = acc[3];
      c_st = sigf(gf)*c_st + sigf(gi)*tanh_(gg);
      float h = sigf(go)*tanh_(c_st);
      // pack (u, u+1) pair -> one dword store (even-kg lanes)
      unsigned short hb16; { _Float16 hh = (_Float16)h; __builtin_memcpy(&hb16, &hh, 2); }
      unsigned partner = __shfl_down((unsigned)hb16, 16);
      if ((kg & 1) == 0)
        myring32[ ((((t&7)*BATCH + bcol)*HID + (wg<<3) + u) >> 1) ] =
            (unsigned)hb16 | (partner << 16);
      if (layer==1 && t==TSEQ-1) hT[bcol*HID + (wg<<3) + u] = h;
    }
    __syncthreads();                       // all waves' h stores drained (vmcnt 0)
    if (tid == 0){
      __threadfence();                     // release: L2 writeback (cross-XCD)
      __hip_atomic_store(&flags[wgAll], (unsigned)(tt+1),
                         __ATOMIC_RELAXED, __HIP_MEMORY_SCOPE_AGENT);
    }
    // ---- prefetch next tick's x-projection (off the critical path)
    int ntt = tt+1;
    bool nact = (layer==0) ? (ntt < TSEQ) : (ntt >= 2 && ntt <= TSEQ+1);
    if (nact){
      accx = floatx4{bias[0], bias[1], bias[2], bias[3]};
      const _Float16* px;
      if (layer == 0){
        int tok = xtok[bcol*TSEQ + ntt];
        px = emb16 + (size_t)tok*HID + kg*8;
      } else {
        // x = h0[ntt-2] published at barrier ntt-2, inv'd since -> fresh
        px = h0ring + (size_t)((ntt-2)&7)*(BATCH*HID) + bcol*HID + kg*8;
      }
      half8 xf[16];
      #pragma unroll
      for (int ks=0; ks<16; ++ks) xf[ks] = *(const half8*)(px + ks*32);
      #pragma unroll
      for (int ks=0; ks<16; ++ks)
        accx = __builtin_amdgcn_mfma_f32_16x16x32_f16(wx[ks], xf[ks], accx, 0,0,0);
    }
    // ---- master-less flag barrier: wave 0 polls all 128 flags
    if (tt <= TSEQ){
      if (wave == 0){
        unsigned tgt = (unsigned)(tt+1);
        for (;;){
          unsigned f0 = __hip_atomic_load(&flags[lane],    __ATOMIC_RELAXED, __HIP_MEMORY_SCOPE_AGENT);
          unsigned f1 = __hip_atomic_load(&flags[64+lane], __ATOMIC_RELAXED, __HIP_MEMORY_SCOPE_AGENT);
          if (__all(f0 >= tgt && f1 >= tgt)) break;
          __builtin_amdgcn_s_sleep(2);
        }
      }
      if (tid == 0) __threadfence();       // acquire: invalidate stale L1/L2
      __syncthreads();
    }
  }
}

// ---------------- classifier + log_softmax + NLL loss
__global__ void k_cls(const float* __restrict__ hT, const float* __restrict__ fcw,
                      const float* __restrict__ fcb, const int* __restrict__ labels,
                      float* __restrict__ out){
  __shared__ float lg[128];
  __shared__ float ls[32];
  int tid = threadIdx.x;
  if (tid < 128){
    int b = tid>>2, n = tid&3;
    const float4* hp = (const float4*)(hT + b*HID);
    const float4* wp = (const float4*)(fcw + n*HID);
    float s = 0.f;
    for (int k=0;k<128;++k){ float4 a = hp[k], w = wp[k];
      s += a.x*w.x + a.y*w.y + a.z*w.z + a.w*w.w; }
    lg[tid] = s + fcb[n];
  }
  __syncthreads();
  if (tid < 32){
    float x0 = lg[tid*4+0], x1 = lg[tid*4+1], x2 = lg[tid*4+2], x3 = lg[tid*4+3];
    float mx = fmaxf(fmaxf(x0,x1),fmaxf(x2,x3));
    float lse = mx + logf(__expf(x0-mx)+__expf(x1-mx)+__expf(x2-mx)+__expf(x3-mx));
    ls[tid] = lse - lg[tid*4 + labels[tid]];
  }
  __syncthreads();
  if (tid == 0){
    float s = 0.f;
    for (int b=0;b<32;++b) s += ls[b];
    out[0] = s * (1.f/32.f);
  }
  if (tid < 128) out[1+tid] = lg[tid];
}

extern "C" void kernel_launch(void* const* d_in, const int* in_sizes, int n_in,
                              void* d_out, int out_size, void* d_ws, size_t ws_size,
                              hipStream_t stream) {
  const int*   x      = (const int*)d_in[0];
  const int*   labels = (const int*)d_in[1];
  const float* emb    = (const float*)d_in[2];
  const float* Wih    = (const float*)d_in[3];
  const float* Whh    = (const float*)d_in[4];
  const float* bih    = (const float*)d_in[5];
  const float* bhh    = (const float*)d_in[6];
  const float* fcw    = (const float*)d_in[7];
  const float* fcb    = (const float*)d_in[8];
  float* out = (float*)d_out;
  char* ws = (char*)d_ws;

  _Float16* emb16  = (_Float16*)(ws);                            // 31.25MB
  _Float16* h0ring = (_Float16*)(ws + (32ull<<20));              // 256KB (8 slots)
  _Float16* h1ring = (_Float16*)(ws + (32ull<<20) + (256<<10));  // 256KB
  float*    hT     = (float*)   (ws + (32ull<<20) + (512<<10));  // 64KB
  unsigned* flags  = (unsigned*)(ws + (32ull<<20) + (576<<10));  // 512B

  hipMemsetAsync(flags, 0, 1024, stream);
  k_cvt_emb<<<8000, 256, 0, stream>>>(emb, emb16, 2048000);
  k_main<<<NWG_ALL, 256, 0, stream>>>(x, emb16, Wih, Whh, bih, bhh,
                                      h0ring, h1ring, hT, flags);
  k_cls<<<1, 256, 0, stream>>>(hT, fcw, fcb, labels, out);
}

// Round 5
// 17798.308 us; speedup vs baseline: 1.4588x; 1.1411x over previous
//
#include <hip/hip_runtime.h>
#include <stdint.h>

// LSTM classifier: VOCAB=32000, H=512, LAYERS=2, LABELS=4, B=32, T=2048
#define TSEQ 2048
#define BATCH 32
#define HID 512
#define NWG_ALL 128      // 64 WGs per layer, each owns 8 hidden units (32 gate rows)

typedef _Float16 half8 __attribute__((ext_vector_type(8)));
typedef float floatx4 __attribute__((ext_vector_type(4)));

__device__ __forceinline__ float sigf(float x){ return 1.f/(1.f+__expf(-x)); }
__device__ __forceinline__ float tanh_(float x){
  float e = __expf(-2.f*fabsf(x));
  float r = (1.f-e)/(1.f+e);
  return x<0.f ? -r : r;
}
__device__ __forceinline__ half8 cvt8(float4 a, float4 b){
  return half8{(_Float16)a.x,(_Float16)a.y,(_Float16)a.z,(_Float16)a.w,
               (_Float16)b.x,(_Float16)b.y,(_Float16)b.z,(_Float16)b.w};
}
// device-coherent 16B load (sc0 sc1 -> MALL, no fence needed)
__device__ __forceinline__ half8 ldh8_coh(const _Float16* p){
  const unsigned long long* q = (const unsigned long long*)p;
  unsigned long long a = __hip_atomic_load(q,   __ATOMIC_RELAXED, __HIP_MEMORY_SCOPE_AGENT);
  unsigned long long b = __hip_atomic_load(q+1, __ATOMIC_RELAXED, __HIP_MEMORY_SCOPE_AGENT);
  union { unsigned long long u[2]; half8 h; } v; v.u[0]=a; v.u[1]=b; return v.h;
}

// ---------------- emb f32 -> f16 (flat convert)
__global__ void k_cvt_emb(const float* __restrict__ in, _Float16* __restrict__ out, int n8){
  int i = blockIdx.x*256 + threadIdx.x;
  if (i < n8){
    const float4* s = (const float4*)(in + (size_t)i*8);
    *(half8*)(out + (size_t)i*8) = cvt8(s[0], s[1]);
  }
}

// ---------------- fused 2-layer persistent LSTM, register-resident weights,
// no LDS, flag-array grid barrier, fence-free MALL-coherent h exchange.
// Gate-row remap: grow(m) = (m&3)*512 + wg*8 + (m>>2); C-frag regs r=0..3 of
// thread (mh,nh,kg,r15) = gates i,f,g,o of unit u=mh*4+kg, batch b=nh*16+r15.
// Layer 1 runs with skew 2: at tick tt it computes step t=tt-2.
__global__ void __launch_bounds__(256,1) k_main(
    const int* __restrict__ xtok, const _Float16* __restrict__ emb16,
    const float* __restrict__ Wih, const float* __restrict__ Whh,
    const float* __restrict__ bih, const float* __restrict__ bhh,
    _Float16* __restrict__ h0ring, _Float16* __restrict__ h1ring,
    float* __restrict__ hT, unsigned* __restrict__ flags){
  int tid = threadIdx.x, lane = tid&63, wave = tid>>6;
  int wgAll = blockIdx.x, layer = wgAll>>6, wg = wgAll&63;
  int mh = wave>>1, nh = wave&1;
  int kg = lane>>4, r15 = lane&15;
  int bcol = nh*16 + r15;           // owned batch column
  int u = mh*4 + kg;                // owned hidden unit (0..7)

  // ---- one-time: weight A-fragments into registers (f32 -> f16)
  half8 wx[16], wh[16];
  {
    int m = mh*16 + r15;            // A-frag row
    int grow = ((m&3)<<9) + (wg<<3) + (m>>2);
    const float* pwx = Wih + ((size_t)layer*2048 + grow)*HID + kg*8;
    const float* pwh = Whh + ((size_t)layer*2048 + grow)*HID + kg*8;
    #pragma unroll
    for (int ks=0; ks<16; ++ks){
      wx[ks] = cvt8(*(const float4*)(pwx + ks*32), *(const float4*)(pwx + ks*32 + 4));
      wh[ks] = cvt8(*(const float4*)(pwh + ks*32), *(const float4*)(pwh + ks*32 + 4));
    }
  }
  float bias[4];
  #pragma unroll
  for (int r=0; r<4; ++r){
    int g = layer*2048 + (r<<9) + (wg<<3) + u;
    bias[r] = bih[g] + bhh[g];
  }

  unsigned* myring32 = (unsigned*)(layer ? h1ring : h0ring);
  const _Float16* hring = layer ? h1ring : h0ring;

  // ---- prologue: x-projection for first active tick
  floatx4 accx = {bias[0], bias[1], bias[2], bias[3]};
  if (layer == 0){
    int tok = xtok[bcol*TSEQ + 0];
    const _Float16* px = emb16 + (size_t)tok*HID + kg*8;
    #pragma unroll
    for (int ks=0; ks<16; ++ks){
      half8 xf = *(const half8*)(px + ks*32);
      accx = __builtin_amdgcn_mfma_f32_16x16x32_f16(wx[ks], xf, accx, 0,0,0);
    }
  }

  float c_st = 0.f;
  for (int tt=0; tt<=TSEQ+1; ++tt){
    bool act = (layer==0) ? (tt < TSEQ) : (tt >= 2);
    int t = (layer==0) ? tt : tt-2;
    if (act){
      floatx4 acc = accx;
      if (t > 0){
        // h_{t-1} B-fragments, device-coherent loads from the ring
        const _Float16* hb = hring + (size_t)((t-1)&7)*(BATCH*HID) + bcol*HID + kg*8;
        half8 hf[16];
        #pragma unroll
        for (int ks=0; ks<16; ++ks) hf[ks] = ldh8_coh(hb + ks*32);
        #pragma unroll
        for (int ks=0; ks<16; ++ks)
          acc = __builtin_amdgcn_mfma_f32_16x16x32_f16(wh[ks], hf[ks], acc, 0,0,0);
      }
      float gi = acc[0], gf = acc[1], gg = acc[2], go = acc[3];
      c_st = sigf(gf)*c_st + sigf(gi)*tanh_(gg);
      float h = sigf(go)*tanh_(c_st);
      // pack (u, u+1) pair -> one coherent dword store (even-kg lanes)
      unsigned short hb16; { _Float16 hh = (_Float16)h; __builtin_memcpy(&hb16, &hh, 2); }
      unsigned partner = __shfl_down((unsigned)hb16, 16);
      if ((kg & 1) == 0)
        __hip_atomic_store(&myring32[ ((((t&7)*BATCH + bcol)*HID + (wg<<3) + u) >> 1) ],
                           (unsigned)hb16 | (partner << 16),
                           __ATOMIC_RELAXED, __HIP_MEMORY_SCOPE_AGENT);
      if (layer==1 && t==TSEQ-1) hT[bcol*HID + (wg<<3) + u] = h;
    }
    __syncthreads();                       // all waves vmcnt(0): h stores MALL-acked
    if (tid == 0)
      __hip_atomic_store(&flags[wgAll], (unsigned)(tt+1),
                         __ATOMIC_RELAXED, __HIP_MEMORY_SCOPE_AGENT);
    // ---- prefetch next tick's x-projection (off the critical path)
    int ntt = tt+1;
    bool nact = (layer==0) ? (ntt < TSEQ) : (ntt >= 2 && ntt <= TSEQ+1);
    if (nact){
      accx = floatx4{bias[0], bias[1], bias[2], bias[3]};
      half8 xf[16];
      if (layer == 0){
        int tok = xtok[bcol*TSEQ + ntt];
        const _Float16* px = emb16 + (size_t)tok*HID + kg*8;
        #pragma unroll
        for (int ks=0; ks<16; ++ks) xf[ks] = *(const half8*)(px + ks*32);
      } else {
        // x = h0[ntt-2], published at barrier (ntt-2) which we already passed
        const _Float16* px = h0ring + (size_t)((ntt-2)&7)*(BATCH*HID) + bcol*HID + kg*8;
        #pragma unroll
        for (int ks=0; ks<16; ++ks) xf[ks] = ldh8_coh(px + ks*32);
      }
      #pragma unroll
      for (int ks=0; ks<16; ++ks)
        accx = __builtin_amdgcn_mfma_f32_16x16x32_f16(wx[ks], xf[ks], accx, 0,0,0);
    }
    // ---- master-less flag barrier: wave 0 polls all 128 flags (MALL loads)
    if (tt <= TSEQ){
      if (wave == 0){
        unsigned tgt = (unsigned)(tt+1);
        for (;;){
          unsigned f0 = __hip_atomic_load(&flags[lane],    __ATOMIC_RELAXED, __HIP_MEMORY_SCOPE_AGENT);
          unsigned f1 = __hip_atomic_load(&flags[64+lane], __ATOMIC_RELAXED, __HIP_MEMORY_SCOPE_AGENT);
          if (__all(f0 >= tgt && f1 >= tgt)) break;
          __builtin_amdgcn_s_sleep(2);
        }
      }
      __syncthreads();
    }
  }
}

// ---------------- classifier + log_softmax + NLL loss
__global__ void k_cls(const float* __restrict__ hT, const float* __restrict__ fcw,
                      const float* __restrict__ fcb, const int* __restrict__ labels,
                      float* __restrict__ out){
  __shared__ float lg[128];
  __shared__ float ls[32];
  int tid = threadIdx.x;
  if (tid < 128){
    int b = tid>>2, n = tid&3;
    const float4* hp = (const float4*)(hT + b*HID);
    const float4* wp = (const float4*)(fcw + n*HID);
    float s = 0.f;
    for (int k=0;k<128;++k){ float4 a = hp[k], w = wp[k];
      s += a.x*w.x + a.y*w.y + a.z*w.z + a.w*w.w; }
    lg[tid] = s + fcb[n];
  }
  __syncthreads();
  if (tid < 32){
    float x0 = lg[tid*4+0], x1 = lg[tid*4+1], x2 = lg[tid*4+2], x3 = lg[tid*4+3];
    float mx = fmaxf(fmaxf(x0,x1),fmaxf(x2,x3));
    float lse = mx + logf(__expf(x0-mx)+__expf(x1-mx)+__expf(x2-mx)+__expf(x3-mx));
    ls[tid] = lse - lg[tid*4 + labels[tid]];
  }
  __syncthreads();
  if (tid == 0){
    float s = 0.f;
    for (int b=0;b<32;++b) s += ls[b];
    out[0] = s * (1.f/32.f);
  }
  if (tid < 128) out[1+tid] = lg[tid];
}

extern "C" void kernel_launch(void* const* d_in, const int* in_sizes, int n_in,
                              void* d_out, int out_size, void* d_ws, size_t ws_size,
                              hipStream_t stream) {
  const int*   x      = (const int*)d_in[0];
  const int*   labels = (const int*)d_in[1];
  const float* emb    = (const float*)d_in[2];
  const float* Wih    = (const float*)d_in[3];
  const float* Whh    = (const float*)d_in[4];
  const float* bih    = (const float*)d_in[5];
  const float* bhh    = (const float*)d_in[6];
  const float* fcw    = (const float*)d_in[7];
  const float* fcb    = (const float*)d_in[8];
  float* out = (float*)d_out;
  char* ws = (char*)d_ws;

  _Float16* emb16  = (_Float16*)(ws);                            // 31.25MB
  _Float16* h0ring = (_Float16*)(ws + (32ull<<20));              // 256KB (8 slots)
  _Float16* h1ring = (_Float16*)(ws + (32ull<<20) + (256<<10));  // 256KB
  float*    hT     = (float*)   (ws + (32ull<<20) + (512<<10));  // 64KB
  unsigned* flags  = (unsigned*)(ws + (32ull<<20) + (576<<10));  // 512B

  hipMemsetAsync(flags, 0, 1024, stream);
  k_cvt_emb<<<8000, 256, 0, stream>>>(emb, emb16, 2048000);
  k_main<<<NWG_ALL, 256, 0, stream>>>(x, emb16, Wih, Whh, bih, bhh,
                                      h0ring, h1ring, hT, flags);
  k_cls<<<1, 256, 0, stream>>>(hT, fcw, fcb, labels, out);
}